// Round 4
// baseline (37578.082 us; speedup 1.0000x reference)
//
#include <hip/hip_runtime.h>
#include <math.h>

#define T_STEPS 2048
#define B_SZ 32
#define F_SZ 512
#define H_SZ 512
#define H4_SZ 2048
#define NC_SZ 64
#define NBLK 64
#define RING32 (B_SZ * H_SZ)   // u32 elements per ring slot (32*512 = 64 KB)

typedef _Float16 f16x8 __attribute__((ext_vector_type(8)));
typedef float f32x4 __attribute__((ext_vector_type(4)));

#define TIDX(l, w, rt, ct) (((((l)*4 + (w))*2 + (rt))*2 + (ct)))

// Ring word = (epoch_tag << 16) | fp16_bits(h). One 4B store is atomic, so
// tag-fresh <=> value-fresh: producer->consumer sync with ZERO extra RTTs
// (no flags, no store drain, no barrier). Rounds 1-3 lesson: every exposed
// LLC RTT in a per-iteration sync chain costs ~µs and they serialize.
__device__ __forceinline__ unsigned ld_frag_tagged(const unsigned* p, unsigned exp,
                                                   f16x8* out) {
    unsigned w[8];
    unsigned diff = 0;
    #pragma unroll
    for (int i = 0; i < 4; ++i) {
        const unsigned long long q = __hip_atomic_load(
            (const unsigned long long*)(p + 2 * i),
            __ATOMIC_RELAXED, __HIP_MEMORY_SCOPE_AGENT);
        w[2 * i]     = (unsigned)q;
        w[2 * i + 1] = (unsigned)(q >> 32);
    }
    #pragma unroll
    for (int i = 0; i < 8; ++i) diff |= (w[i] >> 16) ^ exp;
    union { unsigned u[4]; f16x8 v; } r;
    #pragma unroll
    for (int i = 0; i < 4; ++i)
        r.u[i] = (w[2 * i] & 0xFFFFu) | (w[2 * i + 1] << 16);
    *out = r.v;
    return diff;
}

__device__ __forceinline__ unsigned pack_h(float hv, unsigned tag) {
    union { _Float16 h; unsigned short s; } cv;
    cv.h = (_Float16)hv;
    return (tag << 16) | (unsigned)cv.s;
}

// Dataflow persistent 2-layer LSTM: 64 blocks x 256 thr, block jb owns hidden
// units [8jb,8jb+8) of both layers; c-state in regs; weights in VGPRs.
// Iter it: layer0 t=it, layer1 t=it-1. NO barriers: consumers tag-poll the
// h ring words directly (depth-2 ring provably overwrite-safe under tag sync).
__global__ __launch_bounds__(256, 1) void lstm_persistent(
    const float* __restrict__ feats,
    const float* __restrict__ Wi0, const float* __restrict__ Wh0,
    const float* __restrict__ bh0,
    const float* __restrict__ Wi1, const float* __restrict__ Wh1,
    const float* __restrict__ bh1,
    const float* __restrict__ Wout, const float* __restrict__ bout,
    float* __restrict__ out,
    unsigned* __restrict__ h0ring,   // [2][32][512] tagged u32
    unsigned* __restrict__ h1ring)   // [2][32][512] tagged u32
{
    const int tid   = threadIdx.x;
    const int lane  = tid & 63;
    const int wv    = tid >> 6;          // wave 0..3 = K-quarter of stacked K=1024
    const int jb    = blockIdx.x;        // 0..63
    const int hbase = jb * 8;
    const int rlane = lane & 15;
    const int klo   = (lane >> 4) * 8;

    __shared__ float zs[32 * 272];       // 32 tiles of 16x17 f32 partials
    __shared__ float ps[256];

    // ---- one-time: weight fragments (fp16) ----
    // layer0 stacked K: [Wi0(512); Wh0(512)], A0 = [x | h0]
    // layer1 stacked K: [Wh1(512); Wi1(512)], A1 = [h1 | h0]
    // B frag 16x16x32: lane holds col=lane&15, k=(lane>>4)*8+i  (verified r1)
    f16x8 wf0[2][8], wf1[2][8];
    #pragma unroll
    for (int ct = 0; ct < 2; ++ct) {
        const int cc   = ct * 16 + rlane;
        const int jcol = (cc >> 3) * H_SZ + hbase + (cc & 7);
        #pragma unroll
        for (int ks = 0; ks < 8; ++ks) {
            const int k0 = 256 * wv + 32 * ks + klo;
            f16x8 f0, f1;
            #pragma unroll
            for (int i = 0; i < 8; ++i) {
                const int k = k0 + i;
                const float v0 = (k < H_SZ) ? Wi0[(size_t)k * H4_SZ + jcol]
                                            : Wh0[(size_t)(k - H_SZ) * H4_SZ + jcol];
                const float v1 = (k < H_SZ) ? Wh1[(size_t)k * H4_SZ + jcol]
                                            : Wi1[(size_t)(k - H_SZ) * H4_SZ + jcol];
                f0[i] = (_Float16)v0;
                f1[i] = (_Float16)v1;
            }
            wf0[ct][ks] = f0;
            wf1[ct][ks] = f1;
        }
    }

    // gate-thread mapping: all 256 threads, one (batch,unit) each
    const int gb = tid >> 3, gu = tid & 7;
    const int grow = gb & 15, grt = gb >> 4;
    float c0 = 0.f, c1 = 0.f;
    float bias0[4], bias1[4];
    #pragma unroll
    for (int g = 0; g < 4; ++g) {
        bias0[g] = bh0[g * H_SZ + hbase + gu];
        bias1[g] = bh1[g * H_SZ + hbase + gu];
    }

    f16x8 xf[2][8];   // prefetched+converted x fragments (waves 0,1)

#define PREFETCH_X(tt_) do {                                                         \
    if (wv < 2 && (tt_) < T_STEPS) {                                                 \
        _Pragma("unroll")                                                            \
        for (int rt = 0; rt < 2; ++rt) {                                             \
            const float* xr = feats                                                  \
                + ((size_t)(rt * 16 + rlane) * T_STEPS + (size_t)(tt_)) * F_SZ       \
                + 256 * wv + klo;                                                    \
            _Pragma("unroll")                                                        \
            for (int ks = 0; ks < 8; ++ks) {                                         \
                const float4 p0 = *(const float4*)(xr + 32 * ks);                    \
                const float4 p1 = *(const float4*)(xr + 32 * ks + 4);                \
                f16x8 t;                                                             \
                t[0] = (_Float16)p0.x; t[1] = (_Float16)p0.y;                        \
                t[2] = (_Float16)p0.z; t[3] = (_Float16)p0.w;                        \
                t[4] = (_Float16)p1.x; t[5] = (_Float16)p1.y;                        \
                t[6] = (_Float16)p1.z; t[7] = (_Float16)p1.w;                        \
                xf[rt][ks] = t;                                                      \
            }                                                                        \
        }                                                                            \
    }                                                                                \
} while (0)

    PREFETCH_X(0);

    for (int it = 0; it <= T_STEPS; ++it) {
        // ---- tag-poll + load h fragments (per-wave, no barrier) ----
        // wv>=2: h0[it-1] slot (it+1)&1, expected tag = it   (h0[t] tag = t+1)
        // wv<2 : h1[it-2] slot it&1,     expected tag = it-1 (h1[t] tag = t+1)
        f16x8 hA[2][8];
        if (wv >= 2) {
            const unsigned* hp = h0ring + (size_t)((it + 1) & 1) * RING32;
            const unsigned exp0 = (unsigned)it;
            unsigned diff;
            do {
                diff = 0;
                #pragma unroll
                for (int rt = 0; rt < 2; ++rt)
                    #pragma unroll
                    for (int ks = 0; ks < 8; ++ks)
                        diff |= ld_frag_tagged(hp + (rt * 16 + rlane) * H_SZ
                                               + 256 * (wv - 2) + 32 * ks + klo,
                                               exp0, &hA[rt][ks]);
                if (diff) __builtin_amdgcn_s_sleep(2);
            } while (diff);
        } else if (it > 0) {
            const unsigned* hp = h1ring + (size_t)(it & 1) * RING32;
            const unsigned exp1 = (unsigned)(it - 1);
            unsigned diff;
            do {
                diff = 0;
                #pragma unroll
                for (int rt = 0; rt < 2; ++rt)
                    #pragma unroll
                    for (int ks = 0; ks < 8; ++ks)
                        diff |= ld_frag_tagged(hp + (rt * 16 + rlane) * H_SZ
                                               + 256 * wv + 32 * ks + klo,
                                               exp1, &hA[rt][ks]);
                if (diff) __builtin_amdgcn_s_sleep(2);
            } while (diff);
        }

        const int r0 = (lane >> 4) * 4, ccl = lane & 15;

        // ---- layer0 MFMA (t=it): A = x (wv<2, in regs) or h0 (wv>=2) ----
        if (it < T_STEPS) {
            f32x4 a00 = {0,0,0,0}, a01 = {0,0,0,0}, a10 = {0,0,0,0}, a11 = {0,0,0,0};
            #pragma unroll
            for (int ks = 0; ks < 8; ++ks) {
                const f16x8 ar0 = (wv < 2) ? xf[0][ks] : hA[0][ks];
                const f16x8 ar1 = (wv < 2) ? xf[1][ks] : hA[1][ks];
                a00 = __builtin_amdgcn_mfma_f32_16x16x32_f16(ar0, wf0[0][ks], a00, 0, 0, 0);
                a01 = __builtin_amdgcn_mfma_f32_16x16x32_f16(ar0, wf0[1][ks], a01, 0, 0, 0);
                a10 = __builtin_amdgcn_mfma_f32_16x16x32_f16(ar1, wf0[0][ks], a10, 0, 0, 0);
                a11 = __builtin_amdgcn_mfma_f32_16x16x32_f16(ar1, wf0[1][ks], a11, 0, 0, 0);
            }
            #pragma unroll
            for (int q = 0; q < 4; ++q) {
                zs[TIDX(0, wv, 0, 0) * 272 + (r0 + q) * 17 + ccl] = a00[q];
                zs[TIDX(0, wv, 0, 1) * 272 + (r0 + q) * 17 + ccl] = a01[q];
                zs[TIDX(0, wv, 1, 0) * 272 + (r0 + q) * 17 + ccl] = a10[q];
                zs[TIDX(0, wv, 1, 1) * 272 + (r0 + q) * 17 + ccl] = a11[q];
            }
        }
        // ---- layer1 MFMA (t=it-1): A = h1 (wv<2) or h0 (wv>=2) = hA ----
        if (it > 0) {
            f32x4 a00 = {0,0,0,0}, a01 = {0,0,0,0}, a10 = {0,0,0,0}, a11 = {0,0,0,0};
            #pragma unroll
            for (int ks = 0; ks < 8; ++ks) {
                a00 = __builtin_amdgcn_mfma_f32_16x16x32_f16(hA[0][ks], wf1[0][ks], a00, 0, 0, 0);
                a01 = __builtin_amdgcn_mfma_f32_16x16x32_f16(hA[0][ks], wf1[1][ks], a01, 0, 0, 0);
                a10 = __builtin_amdgcn_mfma_f32_16x16x32_f16(hA[1][ks], wf1[0][ks], a10, 0, 0, 0);
                a11 = __builtin_amdgcn_mfma_f32_16x16x32_f16(hA[1][ks], wf1[1][ks], a11, 0, 0, 0);
            }
            #pragma unroll
            for (int q = 0; q < 4; ++q) {
                zs[TIDX(1, wv, 0, 0) * 272 + (r0 + q) * 17 + ccl] = a00[q];
                zs[TIDX(1, wv, 0, 1) * 272 + (r0 + q) * 17 + ccl] = a01[q];
                zs[TIDX(1, wv, 1, 0) * 272 + (r0 + q) * 17 + ccl] = a10[q];
                zs[TIDX(1, wv, 1, 1) * 272 + (r0 + q) * 17 + ccl] = a11[q];
            }
        }
        __syncthreads();

        // ---- gates: reduce 4 K-partials, update c, store tagged h ----
        if (it < T_STEPS) {
            float z[4];
            #pragma unroll
            for (int g = 0; g < 4; ++g) {
                const int cc = g * 8 + gu, ct = cc >> 4, col = cc & 15;
                float v = bias0[g];
                #pragma unroll
                for (int w = 0; w < 4; ++w)
                    v += zs[TIDX(0, w, grt, ct) * 272 + grow * 17 + col];
                z[g] = v;
            }
            const float ig = 1.f / (1.f + expf(-z[0]));
            const float fg = 1.f / (1.f + expf(-z[1]));
            const float gg = tanhf(z[2]);
            const float og = 1.f / (1.f + expf(-z[3]));
            c0 = fg * c0 + ig * gg;
            const float hv = og * tanhf(c0);
            __hip_atomic_store(
                h0ring + (size_t)(it & 1) * RING32 + gb * H_SZ + hbase + gu,
                pack_h(hv, (unsigned)(it + 1)),
                __ATOMIC_RELAXED, __HIP_MEMORY_SCOPE_AGENT);
        }
        if (it > 0) {
            float z[4];
            #pragma unroll
            for (int g = 0; g < 4; ++g) {
                const int cc = g * 8 + gu, ct = cc >> 4, col = cc & 15;
                float v = bias1[g];
                #pragma unroll
                for (int w = 0; w < 4; ++w)
                    v += zs[TIDX(1, w, grt, ct) * 272 + grow * 17 + col];
                z[g] = v;
            }
            const float ig = 1.f / (1.f + expf(-z[0]));
            const float fg = 1.f / (1.f + expf(-z[1]));
            const float gg = tanhf(z[2]);
            const float og = 1.f / (1.f + expf(-z[3]));
            c1 = fg * c1 + ig * gg;
            const float hv = og * tanhf(c1);
            __hip_atomic_store(
                h1ring + (size_t)((it + 1) & 1) * RING32 + gb * H_SZ + hbase + gu,
                pack_h(hv, (unsigned)it),
                __ATOMIC_RELAXED, __HIP_MEMORY_SCOPE_AGENT);
        }

        // prefetch + convert x[it+1] (overlaps store latency & others' polls)
        PREFETCH_X(it + 1);
        __syncthreads();   // zs reuse protection for next iteration
    }

    // ---- output head: block jb -> out[:, jb]; reads h1[T-1] (tag=T) ring ----
    {
        const unsigned* hf = h1ring + (size_t)((T_STEPS + 1) & 1) * RING32;
        const int b = tid & 31, kc = tid >> 5;
        float part = 0.f;
        #pragma unroll
        for (int c = 0; c < 8; ++c) {
            f16x8 hv8;
            while (ld_frag_tagged(hf + b * H_SZ + kc * 64 + c * 8,
                                  (unsigned)T_STEPS, &hv8))
                __builtin_amdgcn_s_sleep(2);
            #pragma unroll
            for (int j = 0; j < 8; ++j)
                part += (float)hv8[j] * Wout[(size_t)(kc * 64 + c * 8 + j) * NC_SZ + jb];
        }
        ps[kc * 32 + b] = part;
        __syncthreads();
        if (tid < 32) {
            float acc = bout[jb];
            #pragma unroll
            for (int c = 0; c < 8; ++c) acc += ps[c * 32 + tid];
            out[tid * NC_SZ + jb] = acc;
        }
    }
#undef PREFETCH_X
}

extern "C" void kernel_launch(void* const* d_in, const int* in_sizes, int n_in,
                              void* d_out, int out_size, void* d_ws, size_t ws_size,
                              hipStream_t stream) {
    const float* feats = (const float*)d_in[0];
    const float* Wi0   = (const float*)d_in[1];
    const float* Wh0   = (const float*)d_in[2];
    const float* bh0   = (const float*)d_in[3];
    const float* Wi1   = (const float*)d_in[4];
    const float* Wh1   = (const float*)d_in[5];
    const float* bh1   = (const float*)d_in[6];
    const float* Wout  = (const float*)d_in[7];
    const float* bout  = (const float*)d_in[8];

    char* ws = (char*)d_ws;
    unsigned* h0ring = (unsigned*)(ws);            // 2 slots * 64 KB
    unsigned* h1ring = (unsigned*)(ws + 131072);   // 2 slots * 64 KB

    // zero rings each call: value 0, tag 0 == "epoch -1 ready" (determinism —
    // graph replays reuse ws, tags from the prior call MUST be cleared)
    hipMemsetAsync(d_ws, 0, 262144, stream);

    lstm_persistent<<<dim3(NBLK), dim3(256), 0, stream>>>(
        feats, Wi0, Wh0, bh0, Wi1, Wh1, bh1, Wout, bout,
        (float*)d_out, h0ring, h1ring);
}

// Round 6
// 28920.697 us; speedup vs baseline: 1.2993x; 1.2993x over previous
//
#include <hip/hip_runtime.h>
#include <math.h>

#define T_STEPS 2048
#define B_SZ 32
#define F_SZ 512
#define H_SZ 512
#define H4_SZ 2048
#define NC_SZ 64
#define NBLK 64
#define RING (B_SZ * H_SZ)   // fp16 elems per ring slot (32 KB)
#define FLAG_STRIDE 32       // u32s -> 128 B: one LLC line per block's flag

typedef _Float16 f16x8 __attribute__((ext_vector_type(8)));
typedef float f32x4 __attribute__((ext_vector_type(4)));

#define TIDX(l, w, rt, ct) (((((l)*4 + (w))*2 + (rt))*2 + (ct)))

// Batched LLC-coherent h-load: 16 x dwordx4 with sc0 sc1 (bypass L1+L2, read
// the device coherence point) and ONE vmcnt(0) for the whole batch.
// r1-r5 lesson: the h-broadcast floor tracks REQUEST COUNT, not bytes or RTTs
// (r2/r3 8B-requests = 15.5us/iter; r4 same count, 2x bytes ~= same).
// 16B requests cut lane-requests 8x (8192 -> 1024 per block per iter).
// Outputs are true asm outputs, so MFMA consumers are dependency-ordered.
#define LDH16_CP(d, a0, a1)                                                     \
  asm volatile(                                                                 \
    "global_load_dwordx4 %0, %16, off sc0 sc1\n\t"                              \
    "global_load_dwordx4 %1, %16, off offset:64 sc0 sc1\n\t"                    \
    "global_load_dwordx4 %2, %16, off offset:128 sc0 sc1\n\t"                   \
    "global_load_dwordx4 %3, %16, off offset:192 sc0 sc1\n\t"                   \
    "global_load_dwordx4 %4, %16, off offset:256 sc0 sc1\n\t"                   \
    "global_load_dwordx4 %5, %16, off offset:320 sc0 sc1\n\t"                   \
    "global_load_dwordx4 %6, %16, off offset:384 sc0 sc1\n\t"                   \
    "global_load_dwordx4 %7, %16, off offset:448 sc0 sc1\n\t"                   \
    "global_load_dwordx4 %8, %17, off sc0 sc1\n\t"                              \
    "global_load_dwordx4 %9, %17, off offset:64 sc0 sc1\n\t"                    \
    "global_load_dwordx4 %10, %17, off offset:128 sc0 sc1\n\t"                  \
    "global_load_dwordx4 %11, %17, off offset:192 sc0 sc1\n\t"                  \
    "global_load_dwordx4 %12, %17, off offset:256 sc0 sc1\n\t"                  \
    "global_load_dwordx4 %13, %17, off offset:320 sc0 sc1\n\t"                  \
    "global_load_dwordx4 %14, %17, off offset:384 sc0 sc1\n\t"                  \
    "global_load_dwordx4 %15, %17, off offset:448 sc0 sc1\n\t"                  \
    "s_waitcnt vmcnt(0)"                                                        \
    : "=&v"(d[0][0]), "=&v"(d[0][1]), "=&v"(d[0][2]), "=&v"(d[0][3]),           \
      "=&v"(d[0][4]), "=&v"(d[0][5]), "=&v"(d[0][6]), "=&v"(d[0][7]),           \
      "=&v"(d[1][0]), "=&v"(d[1][1]), "=&v"(d[1][2]), "=&v"(d[1][3]),           \
      "=&v"(d[1][4]), "=&v"(d[1][5]), "=&v"(d[1][6]), "=&v"(d[1][7])            \
    : "v"(a0), "v"(a1)                                                          \
    : "memory")

// Single-cluster persistent 2-layer LSTM (r3 structure, known-correct).
// 64 blocks x 256 thr. Block j owns hidden units [8j,8j+8) of BOTH layers
// (c-state in regs). Full batch B=32 per block via 2 MFMA row-tiles.
// Iter it: layer0 t=it, layer1 t=it-1 -> one distributed flag-barrier/iter.
__global__ __launch_bounds__(256, 1) void lstm_persistent(
    const float* __restrict__ feats,
    const float* __restrict__ Wi0, const float* __restrict__ Wh0,
    const float* __restrict__ bh0,
    const float* __restrict__ Wi1, const float* __restrict__ Wh1,
    const float* __restrict__ bh1,
    const float* __restrict__ Wout, const float* __restrict__ bout,
    float* __restrict__ out,
    _Float16* __restrict__ h0buf,   // [2][32][512] fp16 ring
    _Float16* __restrict__ h1buf,   // [2][32][512] fp16 ring
    float* __restrict__ h1fin,      // [32][512] f32 final h1
    unsigned* __restrict__ flags)   // [64 * FLAG_STRIDE] per-block flags, padded
{
    const int tid   = threadIdx.x;
    const int lane  = tid & 63;
    const int wv    = tid >> 6;          // wave 0..3 = K-quarter of stacked K=1024
    const int jb    = blockIdx.x;        // 0..63
    const int hbase = jb * 8;
    const int rlane = lane & 15;
    const int klo   = (lane >> 4) * 8;

    __shared__ float zs[32 * 272];       // 32 tiles of 16x17 f32 partials
    __shared__ float ps[256];

    // ---- one-time: weight fragments (fp16) ----
    // layer0 stacked K: [Wi0(512); Wh0(512)], A0 = [x | h0]
    // layer1 stacked K: [Wh1(512); Wi1(512)], A1 = [h1 | h0]
    // B frag 16x16x32: lane holds col=lane&15, k=(lane>>4)*8+i  (verified r1)
    f16x8 wf0[2][8], wf1[2][8];
    #pragma unroll
    for (int ct = 0; ct < 2; ++ct) {
        const int cc   = ct * 16 + rlane;
        const int jcol = (cc >> 3) * H_SZ + hbase + (cc & 7);
        #pragma unroll
        for (int ks = 0; ks < 8; ++ks) {
            const int k0 = 256 * wv + 32 * ks + klo;
            f16x8 f0, f1;
            #pragma unroll
            for (int i = 0; i < 8; ++i) {
                const int k = k0 + i;
                const float v0 = (k < H_SZ) ? Wi0[(size_t)k * H4_SZ + jcol]
                                            : Wh0[(size_t)(k - H_SZ) * H4_SZ + jcol];
                const float v1 = (k < H_SZ) ? Wh1[(size_t)k * H4_SZ + jcol]
                                            : Wi1[(size_t)(k - H_SZ) * H4_SZ + jcol];
                f0[i] = (_Float16)v0;
                f1[i] = (_Float16)v1;
            }
            wf0[ct][ks] = f0;
            wf1[ct][ks] = f1;
        }
    }

    // gate-thread mapping: all 256 threads, one (batch,unit) each
    const int gb = tid >> 3, gu = tid & 7;
    const int grow = gb & 15, grt = gb >> 4;
    float c0 = 0.f, c1 = 0.f;
    float bias0[4], bias1[4];
    #pragma unroll
    for (int g = 0; g < 4; ++g) {
        bias0[g] = bh0[g * H_SZ + hbase + gu];
        bias1[g] = bh1[g * H_SZ + hbase + gu];
    }

    f16x8 xf[2][8];   // prefetched+converted x fragments (waves 0,1)

#define PREFETCH_X(tt_) do {                                                         \
    if (wv < 2 && (tt_) < T_STEPS) {                                                 \
        _Pragma("unroll")                                                            \
        for (int rt = 0; rt < 2; ++rt) {                                             \
            const float* xr = feats                                                  \
                + ((size_t)(rt * 16 + rlane) * T_STEPS + (size_t)(tt_)) * F_SZ       \
                + 256 * wv + klo;                                                    \
            _Pragma("unroll")                                                        \
            for (int ks = 0; ks < 8; ++ks) {                                         \
                const float4 p0 = *(const float4*)(xr + 32 * ks);                    \
                const float4 p1 = *(const float4*)(xr + 32 * ks + 4);                \
                f16x8 t;                                                             \
                t[0] = (_Float16)p0.x; t[1] = (_Float16)p0.y;                        \
                t[2] = (_Float16)p0.z; t[3] = (_Float16)p0.w;                        \
                t[4] = (_Float16)p1.x; t[5] = (_Float16)p1.y;                        \
                t[6] = (_Float16)p1.z; t[7] = (_Float16)p1.w;                        \
                xf[rt][ks] = t;                                                      \
            }                                                                        \
        }                                                                            \
    }                                                                                \
} while (0)

    PREFETCH_X(0);

    for (int it = 0; it <= T_STEPS; ++it) {
        // ---- distributed barrier: each poll lane owns one padded flag line ----
        if (tid < 64) {
            while (__hip_atomic_load(&flags[(size_t)lane * FLAG_STRIDE],
                                     __ATOMIC_RELAXED, __HIP_MEMORY_SCOPE_AGENT)
                   < (unsigned)it) { }
        }
        __syncthreads();

        // ---- h fragments: wide-batched LLC-coherent loads ----
        // wv>=2: h0[it-1] slot (it+1)&1, shared by layer0 & layer1
        // wv<2 : h1[it-2] slot it&1 for layer1
        f16x8 hA[2][8];
        if (wv >= 2) {
            const _Float16* b0 = h0buf + (size_t)((it + 1) & 1) * RING
                                 + rlane * H_SZ + 256 * (wv - 2) + klo;
            LDH16_CP(hA, b0, b0 + 16 * H_SZ);
        } else if (it > 0) {
            const _Float16* b0 = h1buf + (size_t)(it & 1) * RING
                                 + rlane * H_SZ + 256 * wv + klo;
            LDH16_CP(hA, b0, b0 + 16 * H_SZ);
        }

        const int r0 = (lane >> 4) * 4, ccl = lane & 15;

        // ---- layer0 MFMA (t=it): A = x (wv<2, in regs) or h0 (wv>=2) ----
        if (it < T_STEPS) {
            f32x4 a00 = {0,0,0,0}, a01 = {0,0,0,0}, a10 = {0,0,0,0}, a11 = {0,0,0,0};
            #pragma unroll
            for (int ks = 0; ks < 8; ++ks) {
                const f16x8 ar0 = (wv < 2) ? xf[0][ks] : hA[0][ks];
                const f16x8 ar1 = (wv < 2) ? xf[1][ks] : hA[1][ks];
                a00 = __builtin_amdgcn_mfma_f32_16x16x32_f16(ar0, wf0[0][ks], a00, 0, 0, 0);
                a01 = __builtin_amdgcn_mfma_f32_16x16x32_f16(ar0, wf0[1][ks], a01, 0, 0, 0);
                a10 = __builtin_amdgcn_mfma_f32_16x16x32_f16(ar1, wf0[0][ks], a10, 0, 0, 0);
                a11 = __builtin_amdgcn_mfma_f32_16x16x32_f16(ar1, wf0[1][ks], a11, 0, 0, 0);
            }
            #pragma unroll
            for (int q = 0; q < 4; ++q) {
                zs[TIDX(0, wv, 0, 0) * 272 + (r0 + q) * 17 + ccl] = a00[q];
                zs[TIDX(0, wv, 0, 1) * 272 + (r0 + q) * 17 + ccl] = a01[q];
                zs[TIDX(0, wv, 1, 0) * 272 + (r0 + q) * 17 + ccl] = a10[q];
                zs[TIDX(0, wv, 1, 1) * 272 + (r0 + q) * 17 + ccl] = a11[q];
            }
        }
        // ---- layer1 MFMA (t=it-1): A = h1 (wv<2) or h0 (wv>=2) = hA ----
        if (it > 0) {
            f32x4 a00 = {0,0,0,0}, a01 = {0,0,0,0}, a10 = {0,0,0,0}, a11 = {0,0,0,0};
            #pragma unroll
            for (int ks = 0; ks < 8; ++ks) {
                a00 = __builtin_amdgcn_mfma_f32_16x16x32_f16(hA[0][ks], wf1[0][ks], a00, 0, 0, 0);
                a01 = __builtin_amdgcn_mfma_f32_16x16x32_f16(hA[0][ks], wf1[1][ks], a01, 0, 0, 0);
                a10 = __builtin_amdgcn_mfma_f32_16x16x32_f16(hA[1][ks], wf1[0][ks], a10, 0, 0, 0);
                a11 = __builtin_amdgcn_mfma_f32_16x16x32_f16(hA[1][ks], wf1[1][ks], a11, 0, 0, 0);
            }
            #pragma unroll
            for (int q = 0; q < 4; ++q) {
                zs[TIDX(1, wv, 0, 0) * 272 + (r0 + q) * 17 + ccl] = a00[q];
                zs[TIDX(1, wv, 0, 1) * 272 + (r0 + q) * 17 + ccl] = a01[q];
                zs[TIDX(1, wv, 1, 0) * 272 + (r0 + q) * 17 + ccl] = a10[q];
                zs[TIDX(1, wv, 1, 1) * 272 + (r0 + q) * 17 + ccl] = a11[q];
            }
        }
        __syncthreads();

        // ---- gates: reduce 4 K-partials, update c, store h (agent sc0sc1) ----
        if (it < T_STEPS) {
            float z[4];
            #pragma unroll
            for (int g = 0; g < 4; ++g) {
                const int cc = g * 8 + gu, ct = cc >> 4, col = cc & 15;
                float v = bias0[g];
                #pragma unroll
                for (int w = 0; w < 4; ++w)
                    v += zs[TIDX(0, w, grt, ct) * 272 + grow * 17 + col];
                z[g] = v;
            }
            const float ig = 1.f / (1.f + expf(-z[0]));
            const float fg = 1.f / (1.f + expf(-z[1]));
            const float gg = tanhf(z[2]);
            const float og = 1.f / (1.f + expf(-z[3]));
            c0 = fg * c0 + ig * gg;
            const float hv = og * tanhf(c0);
            const float hpart = __shfl_xor(hv, 1);
            if ((gu & 1) == 0) {   // pack 2 fp16 -> one u32 store
                union { _Float16 h; unsigned short s; } lo, hi;
                lo.h = (_Float16)hv; hi.h = (_Float16)hpart;
                const unsigned pk = (unsigned)lo.s | ((unsigned)hi.s << 16);
                __hip_atomic_store(
                    (unsigned*)(h0buf + (size_t)(it & 1) * RING + gb * H_SZ + hbase + gu),
                    pk, __ATOMIC_RELAXED, __HIP_MEMORY_SCOPE_AGENT);
            }
        }
        if (it > 0) {
            float z[4];
            #pragma unroll
            for (int g = 0; g < 4; ++g) {
                const int cc = g * 8 + gu, ct = cc >> 4, col = cc & 15;
                float v = bias1[g];
                #pragma unroll
                for (int w = 0; w < 4; ++w)
                    v += zs[TIDX(1, w, grt, ct) * 272 + grow * 17 + col];
                z[g] = v;
            }
            const float ig = 1.f / (1.f + expf(-z[0]));
            const float fg = 1.f / (1.f + expf(-z[1]));
            const float gg = tanhf(z[2]);
            const float og = 1.f / (1.f + expf(-z[3]));
            c1 = fg * c1 + ig * gg;
            const float hv = og * tanhf(c1);
            const float hpart = __shfl_xor(hv, 1);
            if ((gu & 1) == 0) {
                union { _Float16 h; unsigned short s; } lo, hi;
                lo.h = (_Float16)hv; hi.h = (_Float16)hpart;
                const unsigned pk = (unsigned)lo.s | ((unsigned)hi.s << 16);
                __hip_atomic_store(
                    (unsigned*)(h1buf + (size_t)((it + 1) & 1) * RING + gb * H_SZ + hbase + gu),
                    pk, __ATOMIC_RELAXED, __HIP_MEMORY_SCOPE_AGENT);
            }
            if (it == T_STEPS) {
                union { float f; unsigned u; } cv; cv.f = hv;
                __hip_atomic_store((unsigned*)(h1fin + gb * H_SZ + hbase + gu),
                                   cv.u, __ATOMIC_RELAXED, __HIP_MEMORY_SCOPE_AGENT);
            }
        }
        // drain all stores to the coherence point, then arrive on own line
        asm volatile("s_waitcnt vmcnt(0)" ::: "memory");
        __syncthreads();
        if (tid == 0)
            __hip_atomic_store(&flags[(size_t)jb * FLAG_STRIDE], (unsigned)(it + 1),
                               __ATOMIC_RELAXED, __HIP_MEMORY_SCOPE_AGENT);

        // tail: prefetch + convert x[it+1] during barrier slack
        PREFETCH_X(it + 1);
    }

    // final barrier: all h1fin stores visible
    if (tid < 64) {
        while (__hip_atomic_load(&flags[(size_t)lane * FLAG_STRIDE],
                                 __ATOMIC_RELAXED, __HIP_MEMORY_SCOPE_AGENT)
               < (unsigned)(T_STEPS + 1)) { }
    }
    __syncthreads();

    // ---- output head: block jb -> out[:, jb] ----
    {
        const int b = tid & 31, kc = tid >> 5;
        float part = 0.f;
        for (int k = kc * 64; k < kc * 64 + 64; ++k) {
            union { unsigned u; float f; } cv;
            cv.u = __hip_atomic_load((const unsigned*)(h1fin + b * H_SZ + k),
                                     __ATOMIC_RELAXED, __HIP_MEMORY_SCOPE_AGENT);
            part += cv.f * Wout[(size_t)k * NC_SZ + jb];
        }
        ps[kc * 32 + b] = part;
        __syncthreads();
        if (tid < 32) {
            float acc = bout[jb];
            #pragma unroll
            for (int c = 0; c < 8; ++c) acc += ps[c * 32 + tid];
            out[tid * NC_SZ + jb] = acc;
        }
    }
#undef PREFETCH_X
}

extern "C" void kernel_launch(void* const* d_in, const int* in_sizes, int n_in,
                              void* d_out, int out_size, void* d_ws, size_t ws_size,
                              hipStream_t stream) {
    const float* feats = (const float*)d_in[0];
    const float* Wi0   = (const float*)d_in[1];
    const float* Wh0   = (const float*)d_in[2];
    const float* bh0   = (const float*)d_in[3];
    const float* Wi1   = (const float*)d_in[4];
    const float* Wh1   = (const float*)d_in[5];
    const float* bh1   = (const float*)d_in[6];
    const float* Wout  = (const float*)d_in[7];
    const float* bout  = (const float*)d_in[8];

    char* ws = (char*)d_ws;
    _Float16* h0buf = (_Float16*)(ws);            // 64 KB
    _Float16* h1buf = (_Float16*)(ws + 65536);    // 64 KB
    float*    h1fin = (float*)(ws + 131072);      // 64 KB
    unsigned* flags = (unsigned*)(ws + 196608);   // 64 * 128 B = 8 KB

    // zero rings (h[-1]=h[-2]=0), final buf, flags — every call (determinism;
    // graph replays reuse ws, so stale flags MUST be cleared each call)
    hipMemsetAsync(d_ws, 0, 204800, stream);

    lstm_persistent<<<dim3(NBLK), dim3(256), 0, stream>>>(
        feats, Wi0, Wh0, bh0, Wi1, Wh1, bh1, Wout, bout,
        (float*)d_out, h0buf, h1buf, h1fin, flags);
}

// Round 7
// 28722.781 us; speedup vs baseline: 1.3083x; 1.0069x over previous
//
#include <hip/hip_runtime.h>
#include <math.h>

#define T_STEPS 2048
#define B_SZ 32
#define F_SZ 512
#define H_SZ 512
#define H4_SZ 2048
#define NC_SZ 64
#define NBLK 64
#define NGRID 256            // 64 workers + 192 heater blocks (DVFS pinning)
#define RING (B_SZ * H_SZ)   // fp16 elems per ring slot (32 KB)
#define FLAG_STRIDE 32       // u32s -> 128 B: one LLC line per block's flag
#define HEAT_CAP (1 << 16)   // heater outer-loop bound (~0.5 s) — can't hang

typedef _Float16 f16x8 __attribute__((ext_vector_type(8)));
typedef float f32x4 __attribute__((ext_vector_type(4)));

#define TIDX(l, w, rt, ct) (((((l)*4 + (w))*2 + (rt))*2 + (ct)))

// Batched LLC-coherent h-load: 16 x dwordx4 with sc0 sc1 (bypass L1+L2, read
// the device coherence point) and ONE vmcnt(0) for the whole batch.
#define LDH16_CP(d, a0, a1)                                                     \
  asm volatile(                                                                 \
    "global_load_dwordx4 %0, %16, off sc0 sc1\n\t"                              \
    "global_load_dwordx4 %1, %16, off offset:64 sc0 sc1\n\t"                    \
    "global_load_dwordx4 %2, %16, off offset:128 sc0 sc1\n\t"                   \
    "global_load_dwordx4 %3, %16, off offset:192 sc0 sc1\n\t"                   \
    "global_load_dwordx4 %4, %16, off offset:256 sc0 sc1\n\t"                   \
    "global_load_dwordx4 %5, %16, off offset:320 sc0 sc1\n\t"                   \
    "global_load_dwordx4 %6, %16, off offset:384 sc0 sc1\n\t"                   \
    "global_load_dwordx4 %7, %16, off offset:448 sc0 sc1\n\t"                   \
    "global_load_dwordx4 %8, %17, off sc0 sc1\n\t"                              \
    "global_load_dwordx4 %9, %17, off offset:64 sc0 sc1\n\t"                    \
    "global_load_dwordx4 %10, %17, off offset:128 sc0 sc1\n\t"                  \
    "global_load_dwordx4 %11, %17, off offset:192 sc0 sc1\n\t"                  \
    "global_load_dwordx4 %12, %17, off offset:256 sc0 sc1\n\t"                  \
    "global_load_dwordx4 %13, %17, off offset:320 sc0 sc1\n\t"                  \
    "global_load_dwordx4 %14, %17, off offset:384 sc0 sc1\n\t"                  \
    "global_load_dwordx4 %15, %17, off offset:448 sc0 sc1\n\t"                  \
    "s_waitcnt vmcnt(0)"                                                        \
    : "=&v"(d[0][0]), "=&v"(d[0][1]), "=&v"(d[0][2]), "=&v"(d[0][3]),           \
      "=&v"(d[0][4]), "=&v"(d[0][5]), "=&v"(d[0][6]), "=&v"(d[0][7]),           \
      "=&v"(d[1][0]), "=&v"(d[1][1]), "=&v"(d[1][2]), "=&v"(d[1][3]),           \
      "=&v"(d[1][4]), "=&v"(d[1][5]), "=&v"(d[1][6]), "=&v"(d[1][7])            \
    : "v"(a0), "v"(a1)                                                          \
    : "memory")

// Persistent 2-layer LSTM (r6 worker structure, known-correct) + heaters.
// Workers: 64 blocks x 256 thr; block j owns hidden units [8j,8j+8) of BOTH
// layers (c-state in regs). Iter it: layer0 t=it, layer1 t=it-1, one
// flag-barrier/iter. Heaters (bid>=64): pure-VALU fma spin to pin DVFS
// clocks high (r1-r6 lesson: all pipes <2% busy -> governor parks the chip
// at floor clock, multiplying every latency in the serial chain ~5-8x; three
// different sync protocols all measured the same 15.5-17us/iter floor).
__global__ __launch_bounds__(256, 1) void lstm_persistent(
    const float* __restrict__ feats,
    const float* __restrict__ Wi0, const float* __restrict__ Wh0,
    const float* __restrict__ bh0,
    const float* __restrict__ Wi1, const float* __restrict__ Wh1,
    const float* __restrict__ bh1,
    const float* __restrict__ Wout, const float* __restrict__ bout,
    float* __restrict__ out,
    _Float16* __restrict__ h0buf,   // [2][32][512] fp16 ring
    _Float16* __restrict__ h1buf,   // [2][32][512] fp16 ring
    float* __restrict__ h1fin,      // [32][512] f32 final h1
    unsigned* __restrict__ flags,   // [64 * FLAG_STRIDE] per-block flags, padded
    unsigned* __restrict__ done)    // heater shutdown flag
{
    const int tid   = threadIdx.x;
    const int jb    = blockIdx.x;

    // ---- heater path: burn VALU until workers finish (bounded) ----
    if (jb >= NBLK) {
        float a = 1.0f, b = 1.000001f, c = 1.0f, d = 0.999999f;
        for (int outer = 0; outer < HEAT_CAP; ++outer) {
            #pragma unroll 64
            for (int i = 0; i < 2048; ++i) {
                a = fmaf(a, b, 1e-7f);
                c = fmaf(c, d, -1e-7f);
            }
            asm volatile("" :: "v"(a), "v"(c));   // keep the chain live
            unsigned f;
            asm volatile("global_load_dword %0, %1, off sc0 sc1\n\t"
                         "s_waitcnt vmcnt(0)"
                         : "=&v"(f) : "v"(done) : "memory");
            if (f) break;
        }
        return;
    }

    const int lane  = tid & 63;
    const int wv    = tid >> 6;          // wave 0..3 = K-quarter of stacked K=1024
    const int hbase = jb * 8;
    const int rlane = lane & 15;
    const int klo   = (lane >> 4) * 8;

    __shared__ float zs[32 * 272];       // 32 tiles of 16x17 f32 partials
    __shared__ float ps[256];

    // ---- one-time: weight fragments (fp16) ----
    // layer0 stacked K: [Wi0(512); Wh0(512)], A0 = [x | h0]
    // layer1 stacked K: [Wh1(512); Wi1(512)], A1 = [h1 | h0]
    // B frag 16x16x32: lane holds col=lane&15, k=(lane>>4)*8+i  (verified r1)
    f16x8 wf0[2][8], wf1[2][8];
    #pragma unroll
    for (int ct = 0; ct < 2; ++ct) {
        const int cc   = ct * 16 + rlane;
        const int jcol = (cc >> 3) * H_SZ + hbase + (cc & 7);
        #pragma unroll
        for (int ks = 0; ks < 8; ++ks) {
            const int k0 = 256 * wv + 32 * ks + klo;
            f16x8 f0, f1;
            #pragma unroll
            for (int i = 0; i < 8; ++i) {
                const int k = k0 + i;
                const float v0 = (k < H_SZ) ? Wi0[(size_t)k * H4_SZ + jcol]
                                            : Wh0[(size_t)(k - H_SZ) * H4_SZ + jcol];
                const float v1 = (k < H_SZ) ? Wh1[(size_t)k * H4_SZ + jcol]
                                            : Wi1[(size_t)(k - H_SZ) * H4_SZ + jcol];
                f0[i] = (_Float16)v0;
                f1[i] = (_Float16)v1;
            }
            wf0[ct][ks] = f0;
            wf1[ct][ks] = f1;
        }
    }

    // gate-thread mapping: all 256 threads, one (batch,unit) each
    const int gb = tid >> 3, gu = tid & 7;
    const int grow = gb & 15, grt = gb >> 4;
    float c0 = 0.f, c1 = 0.f;
    float bias0[4], bias1[4];
    #pragma unroll
    for (int g = 0; g < 4; ++g) {
        bias0[g] = bh0[g * H_SZ + hbase + gu];
        bias1[g] = bh1[g * H_SZ + hbase + gu];
    }

    f16x8 xf[2][8];   // prefetched+converted x fragments (waves 0,1)

#define PREFETCH_X(tt_) do {                                                         \
    if (wv < 2 && (tt_) < T_STEPS) {                                                 \
        _Pragma("unroll")                                                            \
        for (int rt = 0; rt < 2; ++rt) {                                             \
            const float* xr = feats                                                  \
                + ((size_t)(rt * 16 + rlane) * T_STEPS + (size_t)(tt_)) * F_SZ       \
                + 256 * wv + klo;                                                    \
            _Pragma("unroll")                                                        \
            for (int ks = 0; ks < 8; ++ks) {                                         \
                const float4 p0 = *(const float4*)(xr + 32 * ks);                    \
                const float4 p1 = *(const float4*)(xr + 32 * ks + 4);                \
                f16x8 t;                                                             \
                t[0] = (_Float16)p0.x; t[1] = (_Float16)p0.y;                        \
                t[2] = (_Float16)p0.z; t[3] = (_Float16)p0.w;                        \
                t[4] = (_Float16)p1.x; t[5] = (_Float16)p1.y;                        \
                t[6] = (_Float16)p1.z; t[7] = (_Float16)p1.w;                        \
                xf[rt][ks] = t;                                                      \
            }                                                                        \
        }                                                                            \
    }                                                                                \
} while (0)

    PREFETCH_X(0);

    for (int it = 0; it <= T_STEPS; ++it) {
        // ---- distributed barrier: each poll lane owns one padded flag line ----
        if (tid < 64) {
            while (__hip_atomic_load(&flags[(size_t)lane * FLAG_STRIDE],
                                     __ATOMIC_RELAXED, __HIP_MEMORY_SCOPE_AGENT)
                   < (unsigned)it) { }
        }
        __syncthreads();

        // ---- h fragments: wide-batched LLC-coherent loads ----
        // wv>=2: h0[it-1] slot (it+1)&1, shared by layer0 & layer1
        // wv<2 : h1[it-2] slot it&1 for layer1
        f16x8 hA[2][8];
        if (wv >= 2) {
            const _Float16* b0 = h0buf + (size_t)((it + 1) & 1) * RING
                                 + rlane * H_SZ + 256 * (wv - 2) + klo;
            LDH16_CP(hA, b0, b0 + 16 * H_SZ);
        } else if (it > 0) {
            const _Float16* b0 = h1buf + (size_t)(it & 1) * RING
                                 + rlane * H_SZ + 256 * wv + klo;
            LDH16_CP(hA, b0, b0 + 16 * H_SZ);
        }

        const int r0 = (lane >> 4) * 4, ccl = lane & 15;

        // ---- layer0 MFMA (t=it): A = x (wv<2, in regs) or h0 (wv>=2) ----
        if (it < T_STEPS) {
            f32x4 a00 = {0,0,0,0}, a01 = {0,0,0,0}, a10 = {0,0,0,0}, a11 = {0,0,0,0};
            #pragma unroll
            for (int ks = 0; ks < 8; ++ks) {
                const f16x8 ar0 = (wv < 2) ? xf[0][ks] : hA[0][ks];
                const f16x8 ar1 = (wv < 2) ? xf[1][ks] : hA[1][ks];
                a00 = __builtin_amdgcn_mfma_f32_16x16x32_f16(ar0, wf0[0][ks], a00, 0, 0, 0);
                a01 = __builtin_amdgcn_mfma_f32_16x16x32_f16(ar0, wf0[1][ks], a01, 0, 0, 0);
                a10 = __builtin_amdgcn_mfma_f32_16x16x32_f16(ar1, wf0[0][ks], a10, 0, 0, 0);
                a11 = __builtin_amdgcn_mfma_f32_16x16x32_f16(ar1, wf0[1][ks], a11, 0, 0, 0);
            }
            #pragma unroll
            for (int q = 0; q < 4; ++q) {
                zs[TIDX(0, wv, 0, 0) * 272 + (r0 + q) * 17 + ccl] = a00[q];
                zs[TIDX(0, wv, 0, 1) * 272 + (r0 + q) * 17 + ccl] = a01[q];
                zs[TIDX(0, wv, 1, 0) * 272 + (r0 + q) * 17 + ccl] = a10[q];
                zs[TIDX(0, wv, 1, 1) * 272 + (r0 + q) * 17 + ccl] = a11[q];
            }
        }
        // ---- layer1 MFMA (t=it-1): A = h1 (wv<2) or h0 (wv>=2) = hA ----
        if (it > 0) {
            f32x4 a00 = {0,0,0,0}, a01 = {0,0,0,0}, a10 = {0,0,0,0}, a11 = {0,0,0,0};
            #pragma unroll
            for (int ks = 0; ks < 8; ++ks) {
                a00 = __builtin_amdgcn_mfma_f32_16x16x32_f16(hA[0][ks], wf1[0][ks], a00, 0, 0, 0);
                a01 = __builtin_amdgcn_mfma_f32_16x16x32_f16(hA[0][ks], wf1[1][ks], a01, 0, 0, 0);
                a10 = __builtin_amdgcn_mfma_f32_16x16x32_f16(hA[1][ks], wf1[0][ks], a10, 0, 0, 0);
                a11 = __builtin_amdgcn_mfma_f32_16x16x32_f16(hA[1][ks], wf1[1][ks], a11, 0, 0, 0);
            }
            #pragma unroll
            for (int q = 0; q < 4; ++q) {
                zs[TIDX(1, wv, 0, 0) * 272 + (r0 + q) * 17 + ccl] = a00[q];
                zs[TIDX(1, wv, 0, 1) * 272 + (r0 + q) * 17 + ccl] = a01[q];
                zs[TIDX(1, wv, 1, 0) * 272 + (r0 + q) * 17 + ccl] = a10[q];
                zs[TIDX(1, wv, 1, 1) * 272 + (r0 + q) * 17 + ccl] = a11[q];
            }
        }
        __syncthreads();

        // ---- gates: reduce 4 K-partials, update c, store h (agent sc0sc1) ----
        if (it < T_STEPS) {
            float z[4];
            #pragma unroll
            for (int g = 0; g < 4; ++g) {
                const int cc = g * 8 + gu, ct = cc >> 4, col = cc & 15;
                float v = bias0[g];
                #pragma unroll
                for (int w = 0; w < 4; ++w)
                    v += zs[TIDX(0, w, grt, ct) * 272 + grow * 17 + col];
                z[g] = v;
            }
            const float ig = 1.f / (1.f + expf(-z[0]));
            const float fg = 1.f / (1.f + expf(-z[1]));
            const float gg = tanhf(z[2]);
            const float og = 1.f / (1.f + expf(-z[3]));
            c0 = fg * c0 + ig * gg;
            const float hv = og * tanhf(c0);
            const float hpart = __shfl_xor(hv, 1);
            if ((gu & 1) == 0) {   // pack 2 fp16 -> one u32 store
                union { _Float16 h; unsigned short s; } lo, hi;
                lo.h = (_Float16)hv; hi.h = (_Float16)hpart;
                const unsigned pk = (unsigned)lo.s | ((unsigned)hi.s << 16);
                __hip_atomic_store(
                    (unsigned*)(h0buf + (size_t)(it & 1) * RING + gb * H_SZ + hbase + gu),
                    pk, __ATOMIC_RELAXED, __HIP_MEMORY_SCOPE_AGENT);
            }
        }
        if (it > 0) {
            float z[4];
            #pragma unroll
            for (int g = 0; g < 4; ++g) {
                const int cc = g * 8 + gu, ct = cc >> 4, col = cc & 15;
                float v = bias1[g];
                #pragma unroll
                for (int w = 0; w < 4; ++w)
                    v += zs[TIDX(1, w, grt, ct) * 272 + grow * 17 + col];
                z[g] = v;
            }
            const float ig = 1.f / (1.f + expf(-z[0]));
            const float fg = 1.f / (1.f + expf(-z[1]));
            const float gg = tanhf(z[2]);
            const float og = 1.f / (1.f + expf(-z[3]));
            c1 = fg * c1 + ig * gg;
            const float hv = og * tanhf(c1);
            const float hpart = __shfl_xor(hv, 1);
            if ((gu & 1) == 0) {
                union { _Float16 h; unsigned short s; } lo, hi;
                lo.h = (_Float16)hv; hi.h = (_Float16)hpart;
                const unsigned pk = (unsigned)lo.s | ((unsigned)hi.s << 16);
                __hip_atomic_store(
                    (unsigned*)(h1buf + (size_t)((it + 1) & 1) * RING + gb * H_SZ + hbase + gu),
                    pk, __ATOMIC_RELAXED, __HIP_MEMORY_SCOPE_AGENT);
            }
            if (it == T_STEPS) {
                union { float f; unsigned u; } cv; cv.f = hv;
                __hip_atomic_store((unsigned*)(h1fin + gb * H_SZ + hbase + gu),
                                   cv.u, __ATOMIC_RELAXED, __HIP_MEMORY_SCOPE_AGENT);
            }
        }
        // drain all stores to the coherence point, then arrive on own line
        asm volatile("s_waitcnt vmcnt(0)" ::: "memory");
        __syncthreads();
        if (tid == 0)
            __hip_atomic_store(&flags[(size_t)jb * FLAG_STRIDE], (unsigned)(it + 1),
                               __ATOMIC_RELAXED, __HIP_MEMORY_SCOPE_AGENT);

        // tail: prefetch + convert x[it+1] during barrier slack
        PREFETCH_X(it + 1);
    }

    // final barrier: all h1fin stores visible
    if (tid < 64) {
        while (__hip_atomic_load(&flags[(size_t)lane * FLAG_STRIDE],
                                 __ATOMIC_RELAXED, __HIP_MEMORY_SCOPE_AGENT)
               < (unsigned)(T_STEPS + 1)) { }
    }
    __syncthreads();

    // shut the heaters down (any worker may do it; block 0 is first done often)
    if (tid == 0)
        __hip_atomic_store(done, 1u, __ATOMIC_RELAXED, __HIP_MEMORY_SCOPE_AGENT);

    // ---- output head: block jb -> out[:, jb] ----
    {
        const int b = tid & 31, kc = tid >> 5;
        float part = 0.f;
        for (int k = kc * 64; k < kc * 64 + 64; ++k) {
            union { unsigned u; float f; } cv;
            cv.u = __hip_atomic_load((const unsigned*)(h1fin + b * H_SZ + k),
                                     __ATOMIC_RELAXED, __HIP_MEMORY_SCOPE_AGENT);
            part += cv.f * Wout[(size_t)k * NC_SZ + jb];
        }
        ps[kc * 32 + b] = part;
        __syncthreads();
        if (tid < 32) {
            float acc = bout[jb];
            #pragma unroll
            for (int c = 0; c < 8; ++c) acc += ps[c * 32 + tid];
            out[tid * NC_SZ + jb] = acc;
        }
    }
#undef PREFETCH_X
}

extern "C" void kernel_launch(void* const* d_in, const int* in_sizes, int n_in,
                              void* d_out, int out_size, void* d_ws, size_t ws_size,
                              hipStream_t stream) {
    const float* feats = (const float*)d_in[0];
    const float* Wi0   = (const float*)d_in[1];
    const float* Wh0   = (const float*)d_in[2];
    const float* bh0   = (const float*)d_in[3];
    const float* Wi1   = (const float*)d_in[4];
    const float* Wh1   = (const float*)d_in[5];
    const float* bh1   = (const float*)d_in[6];
    const float* Wout  = (const float*)d_in[7];
    const float* bout  = (const float*)d_in[8];

    char* ws = (char*)d_ws;
    _Float16* h0buf = (_Float16*)(ws);            // 64 KB
    _Float16* h1buf = (_Float16*)(ws + 65536);    // 64 KB
    float*    h1fin = (float*)(ws + 131072);      // 64 KB
    unsigned* flags = (unsigned*)(ws + 196608);   // 64 * 128 B = 8 KB
    unsigned* done  = (unsigned*)(ws + 204800);   // heater shutdown flag

    // zero rings (h[-1]=h[-2]=0), final buf, flags, done — every call
    // (graph replays reuse ws; stale flags/done MUST be cleared each call)
    hipMemsetAsync(d_ws, 0, 208896, stream);

    lstm_persistent<<<dim3(NGRID), dim3(256), 0, stream>>>(
        feats, Wi0, Wh0, bh0, Wi1, Wh1, bh1, Wout, bout,
        (float*)d_out, h0buf, h1buf, h1fin, flags, done);
}

// Round 8
// 26309.576 us; speedup vs baseline: 1.4283x; 1.0917x over previous
//
#include <hip/hip_runtime.h>
#include <math.h>

#define T_STEPS 2048
#define B_SZ 32
#define F_SZ 512
#define H_SZ 512
#define H4_SZ 2048
#define NC_SZ 64
#define NBLK 64
#define RINGE 16384          // fp16 elems per ring slot (32 KB), fragment-ordered
#define FLAG_STRIDE 32       // u32s -> 128 B: one LLC line per block's flag

typedef _Float16 f16x8 __attribute__((ext_vector_type(8)));
typedef float f32x4 __attribute__((ext_vector_type(4)));

#define TIDX(l, w, rt, ct) (((((l)*4 + (w))*2 + (rt))*2 + (ct)))

// Fragment-ordered ring layout (the r7 lesson): h ring slot =
//   [kql(2)][ks(8)][rt(2)][lane(64)][i(8)] fp16
// so a consumer wave's 64 lanes load CONTIGUOUS 1KB per dwordx4 instruction.
// Old layout had lanes 1KB apart -> every load splintered into 64 quarter-used
// 64B fabric transactions; per-CU transaction throughput on the L2-bypass
// path was the invariant ~15us/iter floor (survived 3 sync protocols + DVFS
// heaters; only request-efficiency changes ever moved it).
// Consumer: base = slot + kql*8192 + lane*8; frag f=ks*2+rt at byte offset
// f*1024 (4 base regs x offsets 0/1024/2048/3072). One vmcnt(0) for all 16.
#define LDFRAG16(d, a0, a1, a2, a3)                                             \
  asm volatile(                                                                 \
    "global_load_dwordx4 %0, %16, off sc0 sc1\n\t"                              \
    "global_load_dwordx4 %1, %16, off offset:1024 sc0 sc1\n\t"                  \
    "global_load_dwordx4 %2, %16, off offset:2048 sc0 sc1\n\t"                  \
    "global_load_dwordx4 %3, %16, off offset:3072 sc0 sc1\n\t"                  \
    "global_load_dwordx4 %4, %17, off sc0 sc1\n\t"                              \
    "global_load_dwordx4 %5, %17, off offset:1024 sc0 sc1\n\t"                  \
    "global_load_dwordx4 %6, %17, off offset:2048 sc0 sc1\n\t"                  \
    "global_load_dwordx4 %7, %17, off offset:3072 sc0 sc1\n\t"                  \
    "global_load_dwordx4 %8, %18, off sc0 sc1\n\t"                              \
    "global_load_dwordx4 %9, %18, off offset:1024 sc0 sc1\n\t"                  \
    "global_load_dwordx4 %10, %18, off offset:2048 sc0 sc1\n\t"                 \
    "global_load_dwordx4 %11, %18, off offset:3072 sc0 sc1\n\t"                 \
    "global_load_dwordx4 %12, %19, off sc0 sc1\n\t"                             \
    "global_load_dwordx4 %13, %19, off offset:1024 sc0 sc1\n\t"                 \
    "global_load_dwordx4 %14, %19, off offset:2048 sc0 sc1\n\t"                 \
    "global_load_dwordx4 %15, %19, off offset:3072 sc0 sc1\n\t"                 \
    "s_waitcnt vmcnt(0)"                                                        \
    : "=&v"(d[0][0]), "=&v"(d[1][0]), "=&v"(d[0][1]), "=&v"(d[1][1]),           \
      "=&v"(d[0][2]), "=&v"(d[1][2]), "=&v"(d[0][3]), "=&v"(d[1][3]),           \
      "=&v"(d[0][4]), "=&v"(d[1][4]), "=&v"(d[0][5]), "=&v"(d[1][5]),           \
      "=&v"(d[0][6]), "=&v"(d[1][6]), "=&v"(d[0][7]), "=&v"(d[1][7])            \
    : "v"(a0), "v"(a1), "v"(a2), "v"(a3)                                        \
    : "memory")

// Persistent 2-layer LSTM (r6 structure; only the h-ring layout changed).
// 64 blocks x 256 thr. Block j owns hidden units [8j,8j+8) of BOTH layers
// (c-state in regs). Iter it: layer0 t=it, layer1 t=it-1, one flag-barrier.
__global__ __launch_bounds__(256, 1) void lstm_persistent(
    const float* __restrict__ feats,
    const float* __restrict__ Wi0, const float* __restrict__ Wh0,
    const float* __restrict__ bh0,
    const float* __restrict__ Wi1, const float* __restrict__ Wh1,
    const float* __restrict__ bh1,
    const float* __restrict__ Wout, const float* __restrict__ bout,
    float* __restrict__ out,
    _Float16* __restrict__ h0ring,  // [2][RINGE] fp16, fragment-ordered
    _Float16* __restrict__ h1ring,  // [2][RINGE] fp16, fragment-ordered
    float* __restrict__ h1fin,      // [32][512] f32 final h1
    unsigned* __restrict__ flags)   // [64 * FLAG_STRIDE] per-block flags, padded
{
    const int tid   = threadIdx.x;
    const int lane  = tid & 63;
    const int wv    = tid >> 6;          // wave 0..3 = K-quarter of stacked K=1024
    const int jb    = blockIdx.x;        // 0..63
    const int hbase = jb * 8;
    const int rlane = lane & 15;
    const int klo   = (lane >> 4) * 8;

    __shared__ float zs[32 * 272];       // 32 tiles of 16x17 f32 partials
    __shared__ float ps[256];

    // ---- one-time: weight fragments (fp16) ----
    // layer0 stacked K: [Wi0(512); Wh0(512)], A0 = [x | h0]
    // layer1 stacked K: [Wh1(512); Wi1(512)], A1 = [h1 | h0]
    // B frag 16x16x32: lane holds col=lane&15, k=(lane>>4)*8+i  (verified r1)
    f16x8 wf0[2][8], wf1[2][8];
    #pragma unroll
    for (int ct = 0; ct < 2; ++ct) {
        const int cc   = ct * 16 + rlane;
        const int jcol = (cc >> 3) * H_SZ + hbase + (cc & 7);
        #pragma unroll
        for (int ks = 0; ks < 8; ++ks) {
            const int k0 = 256 * wv + 32 * ks + klo;
            f16x8 f0, f1;
            #pragma unroll
            for (int i = 0; i < 8; ++i) {
                const int k = k0 + i;
                const float v0 = (k < H_SZ) ? Wi0[(size_t)k * H4_SZ + jcol]
                                            : Wh0[(size_t)(k - H_SZ) * H4_SZ + jcol];
                const float v1 = (k < H_SZ) ? Wh1[(size_t)k * H4_SZ + jcol]
                                            : Wi1[(size_t)(k - H_SZ) * H4_SZ + jcol];
                f0[i] = (_Float16)v0;
                f1[i] = (_Float16)v1;
            }
            wf0[ct][ks] = f0;
            wf1[ct][ks] = f1;
        }
    }

    // gate-thread mapping: all 256 threads, one (batch,unit) each
    const int gb = tid >> 3, gu = tid & 7;
    const int grow = gb & 15, grt = gb >> 4;
    float c0 = 0.f, c1 = 0.f;
    float bias0[4], bias1[4];
    #pragma unroll
    for (int g = 0; g < 4; ++g) {
        bias0[g] = bh0[g * H_SZ + hbase + gu];
        bias1[g] = bh1[g * H_SZ + hbase + gu];
    }
    // producer scatter index into fragment-ordered ring for value (b=gb,
    // u=hbase+gu): kql=jb>>5, ks=(jb>>2)&7, lane=(jb&3)*16+(gb&15), rt=gb>>4
    const int eidx = (jb >> 5) * 8192
                   + ((((jb >> 2) & 7) * 2) + (gb >> 4)) * 512
                   + ((jb & 3) * 16 + (gb & 15)) * 8 + gu;

    f16x8 xf[2][8];   // prefetched+converted x fragments (waves 0,1)

#define PREFETCH_X(tt_) do {                                                         \
    if (wv < 2 && (tt_) < T_STEPS) {                                                 \
        _Pragma("unroll")                                                            \
        for (int rt = 0; rt < 2; ++rt) {                                             \
            const float* xr = feats                                                  \
                + ((size_t)(rt * 16 + rlane) * T_STEPS + (size_t)(tt_)) * F_SZ       \
                + 256 * wv + klo;                                                    \
            _Pragma("unroll")                                                        \
            for (int ks = 0; ks < 8; ++ks) {                                         \
                const float4 p0 = *(const float4*)(xr + 32 * ks);                    \
                const float4 p1 = *(const float4*)(xr + 32 * ks + 4);                \
                f16x8 t;                                                             \
                t[0] = (_Float16)p0.x; t[1] = (_Float16)p0.y;                        \
                t[2] = (_Float16)p0.z; t[3] = (_Float16)p0.w;                        \
                t[4] = (_Float16)p1.x; t[5] = (_Float16)p1.y;                        \
                t[6] = (_Float16)p1.z; t[7] = (_Float16)p1.w;                        \
                xf[rt][ks] = t;                                                      \
            }                                                                        \
        }                                                                            \
    }                                                                                \
} while (0)

    PREFETCH_X(0);

    for (int it = 0; it <= T_STEPS; ++it) {
        // ---- distributed barrier: each poll lane owns one padded flag line ----
        if (tid < 64) {
            while (__hip_atomic_load(&flags[(size_t)lane * FLAG_STRIDE],
                                     __ATOMIC_RELAXED, __HIP_MEMORY_SCOPE_AGENT)
                   < (unsigned)it) { }
        }
        __syncthreads();

        // ---- h fragments: fully-coalesced fragment-ordered loads ----
        // wv>=2: h0[it-1] slot (it+1)&1, kql=wv-2 (shared by layer0 & layer1)
        // wv<2 : h1[it-2] slot it&1,     kql=wv
        f16x8 hA[2][8];
        if (wv >= 2) {
            const _Float16* b = h0ring + (size_t)((it + 1) & 1) * RINGE
                                + (wv - 2) * 8192 + lane * 8;
            LDFRAG16(hA, b, b + 2048, b + 4096, b + 6144);
        } else if (it > 0) {
            const _Float16* b = h1ring + (size_t)(it & 1) * RINGE
                                + wv * 8192 + lane * 8;
            LDFRAG16(hA, b, b + 2048, b + 4096, b + 6144);
        }

        const int r0 = (lane >> 4) * 4, ccl = lane & 15;

        // ---- layer0 MFMA (t=it): A = x (wv<2, in regs) or h0 (wv>=2) ----
        if (it < T_STEPS) {
            f32x4 a00 = {0,0,0,0}, a01 = {0,0,0,0}, a10 = {0,0,0,0}, a11 = {0,0,0,0};
            #pragma unroll
            for (int ks = 0; ks < 8; ++ks) {
                const f16x8 ar0 = (wv < 2) ? xf[0][ks] : hA[0][ks];
                const f16x8 ar1 = (wv < 2) ? xf[1][ks] : hA[1][ks];
                a00 = __builtin_amdgcn_mfma_f32_16x16x32_f16(ar0, wf0[0][ks], a00, 0, 0, 0);
                a01 = __builtin_amdgcn_mfma_f32_16x16x32_f16(ar0, wf0[1][ks], a01, 0, 0, 0);
                a10 = __builtin_amdgcn_mfma_f32_16x16x32_f16(ar1, wf0[0][ks], a10, 0, 0, 0);
                a11 = __builtin_amdgcn_mfma_f32_16x16x32_f16(ar1, wf0[1][ks], a11, 0, 0, 0);
            }
            #pragma unroll
            for (int q = 0; q < 4; ++q) {
                zs[TIDX(0, wv, 0, 0) * 272 + (r0 + q) * 17 + ccl] = a00[q];
                zs[TIDX(0, wv, 0, 1) * 272 + (r0 + q) * 17 + ccl] = a01[q];
                zs[TIDX(0, wv, 1, 0) * 272 + (r0 + q) * 17 + ccl] = a10[q];
                zs[TIDX(0, wv, 1, 1) * 272 + (r0 + q) * 17 + ccl] = a11[q];
            }
        }
        // ---- layer1 MFMA (t=it-1): A = h1 (wv<2) or h0 (wv>=2) = hA ----
        if (it > 0) {
            f32x4 a00 = {0,0,0,0}, a01 = {0,0,0,0}, a10 = {0,0,0,0}, a11 = {0,0,0,0};
            #pragma unroll
            for (int ks = 0; ks < 8; ++ks) {
                a00 = __builtin_amdgcn_mfma_f32_16x16x32_f16(hA[0][ks], wf1[0][ks], a00, 0, 0, 0);
                a01 = __builtin_amdgcn_mfma_f32_16x16x32_f16(hA[0][ks], wf1[1][ks], a01, 0, 0, 0);
                a10 = __builtin_amdgcn_mfma_f32_16x16x32_f16(hA[1][ks], wf1[0][ks], a10, 0, 0, 0);
                a11 = __builtin_amdgcn_mfma_f32_16x16x32_f16(hA[1][ks], wf1[1][ks], a11, 0, 0, 0);
            }
            #pragma unroll
            for (int q = 0; q < 4; ++q) {
                zs[TIDX(1, wv, 0, 0) * 272 + (r0 + q) * 17 + ccl] = a00[q];
                zs[TIDX(1, wv, 0, 1) * 272 + (r0 + q) * 17 + ccl] = a01[q];
                zs[TIDX(1, wv, 1, 0) * 272 + (r0 + q) * 17 + ccl] = a10[q];
                zs[TIDX(1, wv, 1, 1) * 272 + (r0 + q) * 17 + ccl] = a11[q];
            }
        }
        __syncthreads();

        // ---- gates: reduce 4 K-partials, update c, scatter h into frag ring ----
        if (it < T_STEPS) {
            float z[4];
            #pragma unroll
            for (int g = 0; g < 4; ++g) {
                const int cc = g * 8 + gu, ct = cc >> 4, col = cc & 15;
                float v = bias0[g];
                #pragma unroll
                for (int w = 0; w < 4; ++w)
                    v += zs[TIDX(0, w, grt, ct) * 272 + grow * 17 + col];
                z[g] = v;
            }
            const float ig = 1.f / (1.f + expf(-z[0]));
            const float fg = 1.f / (1.f + expf(-z[1]));
            const float gg = tanhf(z[2]);
            const float og = 1.f / (1.f + expf(-z[3]));
            c0 = fg * c0 + ig * gg;
            const float hv = og * tanhf(c0);
            union { _Float16 h; unsigned short s; } cv; cv.h = (_Float16)hv;
            __hip_atomic_store(
                (unsigned short*)(h0ring + (size_t)(it & 1) * RINGE + eidx),
                cv.s, __ATOMIC_RELAXED, __HIP_MEMORY_SCOPE_AGENT);
        }
        if (it > 0) {
            float z[4];
            #pragma unroll
            for (int g = 0; g < 4; ++g) {
                const int cc = g * 8 + gu, ct = cc >> 4, col = cc & 15;
                float v = bias1[g];
                #pragma unroll
                for (int w = 0; w < 4; ++w)
                    v += zs[TIDX(1, w, grt, ct) * 272 + grow * 17 + col];
                z[g] = v;
            }
            const float ig = 1.f / (1.f + expf(-z[0]));
            const float fg = 1.f / (1.f + expf(-z[1]));
            const float gg = tanhf(z[2]);
            const float og = 1.f / (1.f + expf(-z[3]));
            c1 = fg * c1 + ig * gg;
            const float hv = og * tanhf(c1);
            union { _Float16 h; unsigned short s; } cv; cv.h = (_Float16)hv;
            __hip_atomic_store(
                (unsigned short*)(h1ring + (size_t)((it + 1) & 1) * RINGE + eidx),
                cv.s, __ATOMIC_RELAXED, __HIP_MEMORY_SCOPE_AGENT);
            if (it == T_STEPS) {
                union { float f; unsigned u; } cf; cf.f = hv;
                __hip_atomic_store((unsigned*)(h1fin + gb * H_SZ + hbase + gu),
                                   cf.u, __ATOMIC_RELAXED, __HIP_MEMORY_SCOPE_AGENT);
            }
        }
        // drain all stores to the coherence point, then arrive on own line
        asm volatile("s_waitcnt vmcnt(0)" ::: "memory");
        __syncthreads();
        if (tid == 0)
            __hip_atomic_store(&flags[(size_t)jb * FLAG_STRIDE], (unsigned)(it + 1),
                               __ATOMIC_RELAXED, __HIP_MEMORY_SCOPE_AGENT);

        // tail: prefetch + convert x[it+1] during barrier slack
        PREFETCH_X(it + 1);
    }

    // final barrier: all h1fin stores visible
    if (tid < 64) {
        while (__hip_atomic_load(&flags[(size_t)lane * FLAG_STRIDE],
                                 __ATOMIC_RELAXED, __HIP_MEMORY_SCOPE_AGENT)
               < (unsigned)(T_STEPS + 1)) { }
    }
    __syncthreads();

    // ---- output head: block jb -> out[:, jb] ----
    {
        const int b = tid & 31, kc = tid >> 5;
        float part = 0.f;
        for (int k = kc * 64; k < kc * 64 + 64; ++k) {
            union { unsigned u; float f; } cv;
            cv.u = __hip_atomic_load((const unsigned*)(h1fin + b * H_SZ + k),
                                     __ATOMIC_RELAXED, __HIP_MEMORY_SCOPE_AGENT);
            part += cv.f * Wout[(size_t)k * NC_SZ + jb];
        }
        ps[kc * 32 + b] = part;
        __syncthreads();
        if (tid < 32) {
            float acc = bout[jb];
            #pragma unroll
            for (int c = 0; c < 8; ++c) acc += ps[c * 32 + tid];
            out[tid * NC_SZ + jb] = acc;
        }
    }
#undef PREFETCH_X
}

extern "C" void kernel_launch(void* const* d_in, const int* in_sizes, int n_in,
                              void* d_out, int out_size, void* d_ws, size_t ws_size,
                              hipStream_t stream) {
    const float* feats = (const float*)d_in[0];
    const float* Wi0   = (const float*)d_in[1];
    const float* Wh0   = (const float*)d_in[2];
    const float* bh0   = (const float*)d_in[3];
    const float* Wi1   = (const float*)d_in[4];
    const float* Wh1   = (const float*)d_in[5];
    const float* bh1   = (const float*)d_in[6];
    const float* Wout  = (const float*)d_in[7];
    const float* bout  = (const float*)d_in[8];

    char* ws = (char*)d_ws;
    _Float16* h0ring = (_Float16*)(ws);           // 2 slots * 32 KB
    _Float16* h1ring = (_Float16*)(ws + 131072);  // 2 slots * 32 KB
    float*    h1fin  = (float*)(ws + 262144);     // 64 KB
    unsigned* flags  = (unsigned*)(ws + 327680);  // 64 * 128 B = 8 KB

    // zero rings (h[-1]=h[-2]=0), final buf, flags — every call (determinism;
    // graph replays reuse ws, so stale flags MUST be cleared each call)
    hipMemsetAsync(d_ws, 0, 335872, stream);

    lstm_persistent<<<dim3(NBLK), dim3(256), 0, stream>>>(
        feats, Wi0, Wh0, bh0, Wi1, Wh1, bh1, Wout, bout,
        (float*)d_out, h0ring, h1ring, h1fin, flags);
}